// Round 1
// baseline (473.893 us; speedup 1.0000x reference)
//
#include <hip/hip_runtime.h>
#include <math.h>

#define NG 5
#define NF 5
#define NR 5
#define NW 4
#define STEP 16          // 1 + NG + NF + NR
#define M_OTH 15         // NG + NF + NR
#define NB 60            // NW * M_OTH
#define L 512            // MAXLEN
#define FEAT 64
#define GAMMA 5.0f
#define BIGV 1e10f
#define SEGN 11          // STEP - NR
#define NSEG 44          // NW * SEGN
#define SEGD 32768       // MAXLEN * FEAT

// ---------------------------------------------------------------------------
// K1: pairwise squared distances  D[b][i][j] = ||X[b][i] - Y[b][j]||^2
// one block = 64x64 output tile of one batch; LDS-staged, 4x4 micro-tile.
// ---------------------------------------------------------------------------
__global__ __launch_bounds__(256) void sqdist_kernel(const float* __restrict__ data,
                                                     float* __restrict__ D) {
    int b = blockIdx.z;
    int w = b / M_OTH, m = b % M_OTH;
    const float* X = data + (size_t)(w * STEP) * L * FEAT;            // anchor
    const float* Y = data + (size_t)(w * STEP + 1 + m) * L * FEAT;    // other
    int ti = blockIdx.y * 64;
    int tj = blockIdx.x * 64;

    __shared__ float Xs[64][68];   // pad to 68 floats: float4-aligned rows (272B)
    __shared__ float Ys[64][68];

    int t = threadIdx.y * 16 + threadIdx.x;   // 0..255
    // load 64x64 floats each (1024 float4 per matrix, 4 per thread)
    for (int k = 0; k < 4; ++k) {
        int idx = t + k * 256;        // float4 index
        int r = idx >> 4;             // 16 float4 per row
        int c = (idx & 15) * 4;
        float4 xv = *(const float4*)(X + (size_t)(ti + r) * FEAT + c);
        float4 yv = *(const float4*)(Y + (size_t)(tj + r) * FEAT + c);
        *(float4*)&Xs[r][c] = xv;
        *(float4*)&Ys[r][c] = yv;
    }
    __syncthreads();

    int i0 = threadIdx.y * 4;
    int j0 = threadIdx.x * 4;
    float acc[4][4] = {};
    for (int f = 0; f < FEAT; f += 4) {
        float4 xv[4], yv[4];
        #pragma unroll
        for (int a = 0; a < 4; ++a) xv[a] = *(float4*)&Xs[i0 + a][f];
        #pragma unroll
        for (int c = 0; c < 4; ++c) yv[c] = *(float4*)&Ys[j0 + c][f];
        #pragma unroll
        for (int a = 0; a < 4; ++a)
            #pragma unroll
            for (int c = 0; c < 4; ++c) {
                float d0 = xv[a].x - yv[c].x;
                float d1 = xv[a].y - yv[c].y;
                float d2 = xv[a].z - yv[c].z;
                float d3 = xv[a].w - yv[c].w;
                acc[a][c] += d0 * d0 + d1 * d1 + d2 * d2 + d3 * d3;
            }
    }
    float* Db = D + (size_t)b * L * L;
    #pragma unroll
    for (int a = 0; a < 4; ++a)
        #pragma unroll
        for (int c = 0; c < 4; ++c)
            Db[(size_t)(ti + i0 + a) * L + (tj + j0 + c)] = fmaxf(acc[a][c], 0.0f);
}

// ---------------------------------------------------------------------------
// K2: soft-DTW over anti-diagonals. One block (512 threads) per batch.
// rbuf rotation: rp2 (d-2), rp1 (d-1), rn (d). Thread t handles row i=t+1.
// cell (i, j=d-i): smin over { R(i-1,j)=rp1[i-1], R(i,j-1)=rp1[i], R(i-1,j-1)=rp2[i-1] }
// ---------------------------------------------------------------------------
__global__ __launch_bounds__(512) void sdtw_kernel(const float* __restrict__ D,
                                                   const int* __restrict__ lens,
                                                   float* __restrict__ res) {
    int b = blockIdx.x;
    int w = b / M_OTH, m = b % M_OTH;
    int la = lens[w * STEP];
    int lb = lens[w * STEP + 1 + m];
    int dtar = la + lb;

    __shared__ float rbuf[3][L + 1];
    int t = threadIdx.x;   // 0..511
    int i = t + 1;         // 1..512

    if (t == 0) { rbuf[0][0] = 0.0f; rbuf[1][0] = BIGV; rbuf[2][0] = BIGV; }
    rbuf[0][i] = BIGV;     // r2: BIG except [0]=0
    rbuf[1][i] = BIGV;     // r1: all BIG
    __syncthreads();

    int p2 = 0, p1 = 1, pn = 2;
    const float* Db = D + (size_t)b * L * L + (size_t)(i - 1) * L;   // my row
    const float inv_g = 1.0f / GAMMA;

    float out = 0.0f;
    bool have = false;

    // prefetch D for d=2 (only valid for i=1)
    float Dd = (2 - i >= 1) ? Db[2 - i - 1] : 0.0f;

    for (int d = 2; d <= 2 * L; ++d) {
        int j = d - i;
        // prefetch next-diagonal D value (same row, next column)
        int jn = j + 1;
        float Dnext = (jn >= 1 && jn <= L && d < 2 * L) ? Db[jn - 1] : 0.0f;

        float val;
        if (j >= 1 && j <= L) {
            float a  = rbuf[p1][i - 1];
            float c2 = rbuf[p1][i];
            float c3 = rbuf[p2][i - 1];
            float mn = fminf(a, fminf(c2, c3));
            float s = __expf((mn - a) * inv_g) + __expf((mn - c2) * inv_g) +
                      __expf((mn - c3) * inv_g);
            val = Dd + mn - GAMMA * __logf(s);
        } else {
            val = BIGV;
        }
        rbuf[pn][i] = val;
        if (t == 0) rbuf[pn][0] = BIGV;
        if (d == dtar && i == la) { out = val; have = true; }
        __syncthreads();
        int tmp = p2; p2 = p1; p1 = pn; pn = tmp;
        Dd = Dnext;
    }
    if (have) res[b] = out / (float)(la + lb);
}

// ---------------------------------------------------------------------------
// K3: Gram matrix of the 44 segment vectors (each 32768 floats).
// block (a,b) with a<=b computes dot; writes both symmetric entries.
// ---------------------------------------------------------------------------
__global__ __launch_bounds__(256) void gram_kernel(const float* __restrict__ data,
                                                   float* __restrict__ G) {
    int a = blockIdx.x, bb = blockIdx.y;
    if (bb < a) return;
    int wa = a / SEGN, sa = a % SEGN;
    int wb = bb / SEGN, sb = bb % SEGN;
    const float* va = data + (size_t)(wa * STEP + sa) * SEGD;
    const float* vb = data + (size_t)(wb * STEP + sb) * SEGD;
    int t = threadIdx.x;
    float acc = 0.f;
    for (int k = t * 4; k < SEGD; k += 256 * 4) {
        float4 x = *(const float4*)(va + k);
        float4 y = *(const float4*)(vb + k);
        acc += x.x * y.x + x.y * y.y + x.z * y.z + x.w * y.w;
    }
    __shared__ float red[256];
    red[t] = acc; __syncthreads();
    for (int s = 128; s > 0; s >>= 1) {
        if (t < s) red[t] += red[t + s];
        __syncthreads();
    }
    if (t == 0) { G[a * NSEG + bb] = red[0]; G[bb * NSEG + a] = red[0]; }
}

// ---------------------------------------------------------------------------
// K4: finalize — triplet/hinge/BCE losses from the 60 DTW dists + 9 MMDs
// from the Gram matrix; writes the 2 outputs.
// ---------------------------------------------------------------------------
__global__ __launch_bounds__(512) void finalize_kernel(const float* __restrict__ res,
                                                       const float* __restrict__ G,
                                                       float* __restrict__ out) {
    __shared__ float red[512];
    __shared__ float mmds[9];
    __shared__ float wloss[NW];
    __shared__ int   wnzr[NW];
    int t = threadIdx.x;

    // ---- per-writer losses (threads 0..3) ----
    if (t < NW) {
        int w = t;
        float dg[NG], dn[NF + NR];
        for (int g = 0; g < NG; ++g) dg[g] = res[w * M_OTH + g];
        for (int q = 0; q < NF + NR; ++q) dn[q] = res[w * M_OTH + NG + q];

        float sum_s = 0.f, sum_r = 0.f;
        int nzs = 0, nzr = 0;
        for (int g = 0; g < NG; ++g) {
            for (int f = 0; f < NF; ++f) {
                float v = dg[g] + 1.0f - dn[f];
                if (v > 0.f) { sum_s += v; nzs++; }
            }
            for (int r = 0; r < NR; ++r) {
                float v = dg[g] + 1.5f - dn[NF + r];
                if (v > 0.f) { sum_r += v; nzr++; }
            }
        }
        float ca = (dg[0] + dg[1] + dg[2] + dg[3] + dg[4]) / 5.0f;
        float cb = (dn[0] + dn[1] + dn[2] + dn[3]) * 0.25f;   // dist_n[:, :NW]
        float intra = 0.f;
        for (int g = 0; g < NG; ++g) intra += dg[g] - ca;
        float inter = fmaxf(0.f, 1.0f - fabsf(ca - cb));      // BETA = 1.0
        float lv = (sum_s + sum_r) / (float)(nzs + nzr + 1);
        float bce = 0.f;
        for (int r = 0; r < NR; ++r) {
            float x = dn[NF + r] - dg[0];
            float ls = (x >= 0.f) ? -log1pf(expf(-x)) : (x - log1pf(expf(x)));
            bce += ls;
        }
        bce = -bce / 5.0f;
        wloss[w] = bce + lv + intra * 0.01f + inter * 0.01f;  // P_W = R_W = 0.01
        wnzr[w] = nzr;
    }
    __syncthreads();

    // ---- MMD over 9 writer pairs ----
    const int pi[9] = {0, 0, 0, 1, 1, 2, 2, 3, 3};
    const int pj[9] = {1, 2, 3, 2, 3, 1, 3, 1, 2};
    int pp = t / 22, qq = t % 22;   // valid for t < 484

    for (int p = 0; p < 9; ++p) {
        int wi = pi[p], wj = pj[p];
        float myl2 = 0.f;
        if (t < 484) {
            int gp = (pp < 11) ? wi * SEGN + pp : wj * SEGN + (pp - 11);
            int gq = (qq < 11) ? wi * SEGN + qq : wj * SEGN + (qq - 11);
            float l2 = G[gp * NSEG + gp] + G[gq * NSEG + gq] - 2.f * G[gp * NSEG + gq];
            myl2 = fmaxf(l2, 0.f);
        }
        red[t] = myl2; __syncthreads();
        for (int s = 256; s > 0; s >>= 1) {
            if (t < s) red[t] += red[t + s];
            __syncthreads();
        }
        float bw = red[0] * (1.0f / 462.0f) * 0.25f;   // /(n^2-n) then /KMUL^2
        float kacc = 0.f;
        if (t < 484) {
            float sgn = ((pp < 11) == (qq < 11)) ? 1.f : -1.f;
            float x = -myl2 / bw;
            float e = expf(x) + expf(x * 0.5f) + expf(x * 0.25f) +
                      expf(x * 0.125f) + expf(x * 0.0625f);
            kacc = sgn * e;
        }
        __syncthreads();
        red[t] = kacc; __syncthreads();
        for (int s = 256; s > 0; s >>= 1) {
            if (t < s) red[t] += red[t + s];
            __syncthreads();
        }
        if (t == 0) mmds[p] = red[0] / 121.0f;
        __syncthreads();
    }

    if (t == 0) {
        float loss = 0.25f * (wloss[0] + wloss[1] + wloss[2] + wloss[3]);
        float mx = 0.f;   // mmds vector is zero-padded to 10 in the reference
        for (int p = 0; p < 9; ++p) mx = fmaxf(mx, mmds[p]);
        out[0] = loss + 0.1f * mx;    // ALPHA = 0.1
        out[1] = (float)(wnzr[0] + wnzr[1] + wnzr[2] + wnzr[3]);
    }
}

// ---------------------------------------------------------------------------
extern "C" void kernel_launch(void* const* d_in, const int* in_sizes, int n_in,
                              void* d_out, int out_size, void* d_ws, size_t ws_size,
                              hipStream_t stream) {
    const float* data = (const float*)d_in[0];
    const int* lens = (const int*)d_in[1];

    float* D   = (float*)d_ws;                               // 60*512*512 floats
    float* res = D + (size_t)NB * L * L;                     // 60 floats
    float* G   = res + 64;                                   // 44*44 floats
    float* out = (float*)d_out;

    dim3 g1(8, 8, NB), b1(16, 16);
    sqdist_kernel<<<g1, b1, 0, stream>>>(data, D);
    sdtw_kernel<<<NB, 512, 0, stream>>>(D, lens, res);
    dim3 g3(NSEG, NSEG);
    gram_kernel<<<g3, 256, 0, stream>>>(data, G);
    finalize_kernel<<<1, 512, 0, stream>>>(res, G, out);
}